// Round 7
// baseline (29910.703 us; speedup 1.0000x reference)
//
#include <hip/hip_runtime.h>
#include <cstdint>
#include <cstddef>

// Problem dims: B=32, T=2048, D=512, H=512, 4H=2048
#define TT 2048
#define DD 512

// ---------------------------------------------------------------------------
// Phase 1 (chunked): xp = inputs @ Wi + b, layout: xp[tl][gate 4][B 32][col 512]
// fp32 vector GEMM, 128x128x16 tiles, 8x8 per thread.  (unchanged)
// ---------------------------------------------------------------------------
#define BM 128
#define BN 128
#define BK 16

__global__ __launch_bounds__(256) void xproj_gemm(
    const float* __restrict__ A,    // [32*2048, 512]
    const float* __restrict__ W,    // [512, 2048]
    const float* __restrict__ bias, // [2048]
    float* __restrict__ C,          // xp chunk
    int t0, int tmask, int tlog)    // T_CH = tmask+1 = 1<<tlog
{
    __shared__ __align__(16) float As[BK][BM + 4];   // [k][m], transposed on load
    __shared__ __align__(16) float Bs[BK][BN + 4];   // [k][n]
    const int tid = threadIdx.x;
    const int nt = blockIdx.x;
    const int mt = blockIdx.y;
    const int m_base = mt * BM;        // chunk-local row (m = bglob*T_CH + tl)
    const int n_base = nt * BN;
    const int ty = tid >> 4;
    const int tx = tid & 15;

    float acc[8][8];
#pragma unroll
    for (int i = 0; i < 8; ++i)
#pragma unroll
        for (int j = 0; j < 8; ++j) acc[i][j] = 0.f;

    for (int k0 = 0; k0 < DD; k0 += BK) {
#pragma unroll
        for (int j = 0; j < 2; ++j) {
            int idx = tid * 2 + j;             // 0..511
            int rowl = idx >> 2, q = idx & 3;  // A: 128 rows x 4 float4
            int rc = m_base + rowl;            // chunk-local row
            int rg = ((rc >> tlog) << 11) + t0 + (rc & tmask);  // global input row
            float4 av = *(const float4*)(A + (size_t)rg * DD + k0 + q * 4);
            As[q * 4 + 0][rowl] = av.x;
            As[q * 4 + 1][rowl] = av.y;
            As[q * 4 + 2][rowl] = av.z;
            As[q * 4 + 3][rowl] = av.w;
            int kr = idx >> 5, nq = idx & 31;  // B: 16 rows x 32 float4
            *(float4*)&Bs[kr][nq * 4] =
                *(const float4*)(W + (size_t)(k0 + kr) * 2048 + n_base + nq * 4);
        }
        __syncthreads();
#pragma unroll
        for (int kk = 0; kk < BK; ++kk) {
            float a[8], bb[8];
            *(float4*)&a[0]  = *(const float4*)&As[kk][ty * 8];
            *(float4*)&a[4]  = *(const float4*)&As[kk][ty * 8 + 4];
            *(float4*)&bb[0] = *(const float4*)&Bs[kk][tx * 8];
            *(float4*)&bb[4] = *(const float4*)&Bs[kk][tx * 8 + 4];
#pragma unroll
            for (int i = 0; i < 8; ++i)
#pragma unroll
                for (int j = 0; j < 8; ++j)
                    acc[i][j] = fmaf(a[i], bb[j], acc[i][j]);
        }
        __syncthreads();
    }
#pragma unroll
    for (int i = 0; i < 8; ++i) {
        int m = m_base + ty * 8 + i;
        int bglob = m >> tlog, tl = m & tmask;
#pragma unroll
        for (int j = 0; j < 8; j += 4) {
            int n = n_base + tx * 8 + j;
            int gate = n >> 9, c = n & 511;    // 8-aligned run never crosses gate
            float4 v;
            v.x = acc[i][j + 0] + bias[n + 0];
            v.y = acc[i][j + 1] + bias[n + 1];
            v.z = acc[i][j + 2] + bias[n + 2];
            v.w = acc[i][j + 3] + bias[n + 3];
            size_t addr = (((size_t)tl * 4 + gate) * 32 + bglob) * 512 + c;
            *(float4*)(C + addr) = v;
        }
    }
}

// ---------------------------------------------------------------------------
// Phase 2: persistent LSTM scan — BARRIER-FREE step.
// Wh slice in LDS (R6's proven plan, re-read per step). h is loaded per-lane
// DIRECTLY from hbuf into registers (16 x 8B agent loads = the wave's exact
// dot operands); the poll and the data load are the same instructions, and
// __all over the wave verifies the FULL group h (= the poison-safety
// precondition). Zero __syncthreads in the step loop: each wave is an
// independent pipeline {poll/load -> dot -> butterfly -> gates -> per-wave
// vmcnt drain -> h-store + poison}; wave skew is absorbed by the 3-buffer
// rotation.
//
// Geometry (R6): 8 groups x 32 blocks x 512 threads (1 block/CU). Group g
// owns batches [4g,4g+4). Block p owns cols [16p,16p+16). Wave w owns cols
// {16p+2w, 16p+2w+1}, all 4 gates, all 4 batches. Lane l owns
// k in {4l..4l+3} U {256+4l..256+4l+3}. Dot order, butterfly, bitrev role
// map and gate math are verbatim R6 -> bit-identical numerics.
//
// Poison protocol (R4/R6-proven): h rotates through 3 buffers; after the
// wave-wide poll of complete h_t (which proves every group wave finished
// step t-1, i.e. consumed h_{t-1}), act lanes poison their slot of the
// recycle buffer; the vmcnt(0) drain orders poison (and everything older)
// before the h_{t+1} store (drain-then-signal, data = signal). 0xFFFFFFFF
// is NaN, unreachable by h = o*tanh(c) in (-1,1).
// ---------------------------------------------------------------------------
#define NGRP 8
#define BPG  32
#define HSZ  (32 * 512)          // one h buffer (floats)
#define POISON 0xFFFFFFFFu
#define WHST 516                 // padded wh row stride (floats, mult of 4)

__device__ __forceinline__ float2 ldg_agent_f2(const float* p) {
    double d = __hip_atomic_load((const double*)p, __ATOMIC_RELAXED,
                                 __HIP_MEMORY_SCOPE_AGENT);
    return __builtin_bit_cast(float2, d);
}

// butterfly reduce step: halve the live value count across lanes differing in bit D
template<int D, int HALF>
__device__ __forceinline__ void rstep(float* p, int lane) {
    const bool hi = (lane & D) != 0;
#pragma unroll
    for (int i = 0; i < HALF; ++i) {
        float send = hi ? p[i] : p[i + HALF];
        float recv = __shfl_xor(send, D, 64);
        p[i] = (hi ? p[i + HALF] : p[i]) + recv;
    }
}

__global__ __launch_bounds__(512) void lstm_scan(
    const float* __restrict__ xp,   // [tl][gate 4][B 32][col 512]
    const float* __restrict__ Wh,   // [512, 2048]
    const float* __restrict__ c0,   // [32, 512]
    const float* __restrict__ h0,   // [32, 512]
    float* __restrict__ out,        // [32, 2048, 512]
    float* hbuf,                    // [3][32][512] rotating (persists)
    float* __restrict__ cbuf,       // [32][512] c-state (persists)
    int t0, int T_CH)
{
    __shared__ float wh[64 * WHST];   // [gate*16 + local_col][k]  132,096 B

    const int tid  = threadIdx.x;
    const int blk  = blockIdx.x;
    const int g    = blk >> 5;      // group 0..7 (4 batches each)
    const int p    = blk & 31;      // block-in-group (16 cols each)
    const int j0   = p * 16;
    const int lane = tid & 63;
    const int w    = tid >> 6;      // wave 0..7

    // lane<32 role decode: idx = bitrev5(lane) = gate*8 + cc*4 + b
    const int idx = ((lane & 1) << 4) | ((lane & 2) << 2) | (lane & 4)
                  | ((lane >> 2) & 2) | ((lane >> 4) & 1);
    const int gate = idx >> 3;
    const int cc   = (idx >> 2) & 1;
    const int bq   = idx & 3;
    const int B    = 4 * g + bq;
    const int col  = j0 + 2 * w + cc;
    const bool low = lane < 32;
    const bool act = low && ((lane & 3) == 0);   // gate==0 owner lanes

    // ---- h0 / creg init (issue h0 stores FIRST so peers' polls clear) ----
    float creg = 0.f;
    if (act) {
        size_t o = (size_t)B * 512 + col;
        if (t0 == 0) {
            creg = c0[o];
            float hv = h0[o];
            if (__float_as_uint(hv) == POISON) hv = __uint_as_float(0xFFFFFFFEu);
            __hip_atomic_store(hbuf + o, hv, __ATOMIC_RELAXED, __HIP_MEMORY_SCOPE_AGENT);
        } else {
            creg = cbuf[o];   // h_{t0} already in hbuf[t0%3] from prev chunk
        }
    }

    // ---- stage Wh slice into LDS (once per launch) ----
    // wh[(gt*16 + lc)][k] = Wh[k][gt*512 + j0 + lc], lc = 0..15
#pragma unroll
    for (int i = 0; i < 16; ++i) {
        int id = tid + i * 512;            // 0..8191
        int q4 = id & 3, gt = (id >> 2) & 3, k = id >> 4;
        float4 v = *(const float4*)(Wh + (size_t)k * 2048 + gt * 512 + j0 + q4 * 4);
        int r0 = gt * 16 + q4 * 4;
        wh[(r0 + 0) * WHST + k] = v.x;
        wh[(r0 + 1) * WHST + k] = v.y;
        wh[(r0 + 2) * WHST + k] = v.z;
        wh[(r0 + 3) * WHST + k] = v.w;
    }

    // xp prefetch for tl=0 (one float per low lane: its (gate,B,col))
    float xr = 0.f, xn = 0.f;
    if (low) xr = xp[((size_t)gate * 32 + B) * 512 + col];

    __syncthreads();   // wh ready (only barrier; none inside the step loop)

    for (int tl = 0; tl < T_CH; ++tl) {
        const int t = t0 + tl;
        const int cur = t % 3;             // read h_t
        const int nxt = (t + 1) % 3;       // write h_{t+1}
        const int rcy = (t + 2) % 3;       // poison own slot (holds dead h_{t-1})

        // issue next-step xp prefetch (in flight across poll+dot)
        if (low && (tl + 1 < T_CH))
            xn = xp[((size_t)((tl + 1) * 4 + gate) * 32 + B) * 512 + col];

        // ---- poll == load: lane's 32 h operands (4 batches x 8 k), retry on
        // poison; __all makes the wave collectively verify the FULL group h ----
        float2 hlo[4][2], hhi[4][2];   // [b][pair]: k {4l,4l+1},{4l+2,4l+3}, +256
        {
            const float* hb = hbuf + (size_t)cur * HSZ
                            + (size_t)(4 * g) * 512 + 4 * lane;
            for (;;) {
                bool ok = true;
#pragma unroll
                for (int b = 0; b < 4; ++b) {
                    const float* pb = hb + b * 512;
                    hlo[b][0] = ldg_agent_f2(pb);
                    hlo[b][1] = ldg_agent_f2(pb + 2);
                    hhi[b][0] = ldg_agent_f2(pb + 256);
                    hhi[b][1] = ldg_agent_f2(pb + 258);
#pragma unroll
                    for (int q = 0; q < 2; ++q) {
                        ok = ok & (__float_as_uint(hlo[b][q].x) != POISON)
                               & (__float_as_uint(hlo[b][q].y) != POISON)
                               & (__float_as_uint(hhi[b][q].x) != POISON)
                               & (__float_as_uint(hhi[b][q].y) != POISON);
                    }
                }
                if (__all(ok)) break;
                __builtin_amdgcn_s_sleep(1);
            }
        }
        // keep the poison store below the poll (no compiler hoisting)
        __builtin_amdgcn_sched_barrier(0);

        // ---- poison recycle slot (safe: complete h_t implies every group
        // wave finished step t-1, i.e. consumed h_{t-1}) ----
        if (act)
            __hip_atomic_store(hbuf + (size_t)rcy * HSZ + (size_t)B * 512 + col,
                               __uint_as_float(POISON),
                               __ATOMIC_RELAXED, __HIP_MEMORY_SCOPE_AGENT);

        // ---- dot: pp[gate*8 + cc*4 + b] over this lane's 8 k (order = R6) ----
        float pp[32];
#pragma unroll
        for (int i = 0; i < 32; ++i) pp[i] = 0.f;
#pragma unroll
        for (int gt = 0; gt < 4; ++gt)
#pragma unroll
            for (int c2 = 0; c2 < 2; ++c2) {
                const float* wr = wh + (size_t)(gt * 16 + 2 * w + c2) * WHST + 4 * lane;
                float4 w0 = *(const float4*)wr;
                float4 w1 = *(const float4*)(wr + 256);
#pragma unroll
                for (int b = 0; b < 4; ++b) {
                    float a = pp[gt * 8 + c2 * 4 + b];
                    a = fmaf(hlo[b][0].x, w0.x, a);
                    a = fmaf(hlo[b][0].y, w0.y, a);
                    a = fmaf(hlo[b][1].x, w0.z, a);
                    a = fmaf(hlo[b][1].y, w0.w, a);
                    a = fmaf(hhi[b][0].x, w1.x, a);
                    a = fmaf(hhi[b][0].y, w1.y, a);
                    a = fmaf(hhi[b][1].x, w1.z, a);
                    a = fmaf(hhi[b][1].y, w1.w, a);
                    pp[gt * 8 + c2 * 4 + b] = a;
                }
            }

        // ---- butterfly: lane ends with total for idx = bitrev5(lane&31) ----
        rstep<1, 16>(pp, lane);
        rstep<2, 8>(pp, lane);
        rstep<4, 4>(pp, lane);
        rstep<8, 2>(pp, lane);
        rstep<16, 1>(pp, lane);
        float v0 = pp[0] + __shfl_xor(pp[0], 32, 64);

        // ---- distributed activation: each low lane applies its gate's fn ----
        float av = 0.f;
        if (low) {
            float zz = v0 + xr;
            av = (gate == 2) ? tanhf(zz) : 1.f / (1.f + expf(-zz));
        }
        // gathers (R3/R5/R6-verified): xor1 -> g, xor2 -> f, xor3 -> o
        float ag = __shfl_xor(av, 1, 64);
        float af = __shfl_xor(av, 2, 64);
        float ao = __shfl_xor(av, 3, 64);

        float hn = 0.f;
        if (act) {
            float cn = af * creg + av * ag;   // sf*c + si*tg
            hn = ao * tanhf(cn);
            creg = cn;
        }
        // drain: poison (issued pre-dot, long acked) + everything older at the
        // coherence point BEFORE h_{t+1} becomes visible.
        asm volatile("s_waitcnt vmcnt(0)" ::: "memory");
        if (act) {
            __hip_atomic_store(hbuf + (size_t)nxt * HSZ + (size_t)B * 512 + col,
                               hn, __ATOMIC_RELAXED, __HIP_MEMORY_SCOPE_AGENT);
            out[((size_t)B * TT + t) * 512 + col] = hn;   // post-critical-path
        }
        if (low) xr = xn;
    }

    // persist c for next chunk launch (plain; kernel-boundary coherence)
    if (act) cbuf[(size_t)B * 512 + col] = creg;
}

// ---------------------------------------------------------------------------
extern "C" void kernel_launch(void* const* d_in, const int* in_sizes, int n_in,
                              void* d_out, int out_size, void* d_ws, size_t ws_size,
                              hipStream_t stream) {
    const float* inputs = (const float*)d_in[0];
    // d_in[1] = input_paddings: unused (reference discards it)
    const float* c0   = (const float*)d_in[2];
    const float* h0   = (const float*)d_in[3];
    const float* Wi   = (const float*)d_in[4];
    const float* Wh   = (const float*)d_in[5];
    const float* bias = (const float*)d_in[6];
    float* out = (float*)d_out;

    // ws layout (floats): [hbuf 3*16384][cbuf 16384][xp]
    float* ws_f = (float*)d_ws;
    float* hbuf = ws_f;                              // 49152 floats
    float* cbuf = ws_f + 3 * HSZ;                    // 16384 floats
    float* xp   = ws_f + 4 * HSZ;                    // offset 65536 (16B aligned)
    const size_t extras_bytes = (size_t)(4 * HSZ) * sizeof(float);

    // pick largest T-chunk (pow2, <=256) whose xp slab fits in ws
    int T_CH = 256;
    while (T_CH > 32 &&
           extras_bytes + (size_t)T_CH * 65536 * sizeof(float) > ws_size)
        T_CH >>= 1;
    int tlog = 31 - __builtin_clz((unsigned)T_CH);

    // poison all 3 h buffers (0xFF bytes -> 0xFFFFFFFF words) before t0=0;
    // the scan kernel fills buf[0] with h0 in-kernel (polling is the sync).
    hipMemsetAsync(hbuf, 0xFF, (size_t)(3 * HSZ) * sizeof(float), stream);

    for (int t0 = 0; t0 < TT; t0 += T_CH) {
        dim3 g1(2048 / BN, (32 * T_CH) / BM);
        xproj_gemm<<<g1, 256, 0, stream>>>(inputs, Wi, bias, xp, t0, T_CH - 1, tlog);

        const float* xp_c = xp;
        int t0_arg = t0, tch_arg = T_CH;
        void* args[] = { (void*)&xp_c, (void*)&Wh, (void*)&c0, (void*)&h0,
                         (void*)&out, (void*)&hbuf, (void*)&cbuf,
                         (void*)&t0_arg, (void*)&tch_arg };
        hipLaunchCooperativeKernel((const void*)lstm_scan, dim3(NGRP * BPG), dim3(512),
                                   args, 0, stream);
    }
}

// Round 8
// 8308.579 us; speedup vs baseline: 3.6000x; 3.6000x over previous
//
#include <hip/hip_runtime.h>
#include <cstdint>
#include <cstddef>

// Problem dims: B=32, T=2048, D=512, H=512, 4H=2048
#define TT 2048
#define DD 512

// ---------------------------------------------------------------------------
// Phase 1 (prologue / serial fallback): xp = inputs @ Wi + b,
// layout: xp[tl][gate 4][B 32][col 512]. 128x128x16 tiles. (unchanged)
// ---------------------------------------------------------------------------
#define BM 128
#define BN 128
#define BK 16

__global__ __launch_bounds__(256) void xproj_gemm(
    const float* __restrict__ A,    // [32*2048, 512]
    const float* __restrict__ W,    // [512, 2048]
    const float* __restrict__ bias, // [2048]
    float* __restrict__ C,          // xp chunk
    int t0, int tmask, int tlog)    // T_CH = tmask+1 = 1<<tlog
{
    __shared__ __align__(16) float As[BK][BM + 4];   // [k][m], transposed on load
    __shared__ __align__(16) float Bs[BK][BN + 4];   // [k][n]
    const int tid = threadIdx.x;
    const int nt = blockIdx.x;
    const int mt = blockIdx.y;
    const int m_base = mt * BM;
    const int n_base = nt * BN;
    const int ty = tid >> 4;
    const int tx = tid & 15;

    float acc[8][8];
#pragma unroll
    for (int i = 0; i < 8; ++i)
#pragma unroll
        for (int j = 0; j < 8; ++j) acc[i][j] = 0.f;

    for (int k0 = 0; k0 < DD; k0 += BK) {
#pragma unroll
        for (int j = 0; j < 2; ++j) {
            int idx = tid * 2 + j;             // 0..511
            int rowl = idx >> 2, q = idx & 3;  // A: 128 rows x 4 float4
            int rc = m_base + rowl;            // chunk-local row
            int rg = ((rc >> tlog) << 11) + t0 + (rc & tmask);
            float4 av = *(const float4*)(A + (size_t)rg * DD + k0 + q * 4);
            As[q * 4 + 0][rowl] = av.x;
            As[q * 4 + 1][rowl] = av.y;
            As[q * 4 + 2][rowl] = av.z;
            As[q * 4 + 3][rowl] = av.w;
            int kr = idx >> 5, nq = idx & 31;  // B: 16 rows x 32 float4
            *(float4*)&Bs[kr][nq * 4] =
                *(const float4*)(W + (size_t)(k0 + kr) * 2048 + n_base + nq * 4);
        }
        __syncthreads();
#pragma unroll
        for (int kk = 0; kk < BK; ++kk) {
            float a[8], bb[8];
            *(float4*)&a[0]  = *(const float4*)&As[kk][ty * 8];
            *(float4*)&a[4]  = *(const float4*)&As[kk][ty * 8 + 4];
            *(float4*)&bb[0] = *(const float4*)&Bs[kk][tx * 8];
            *(float4*)&bb[4] = *(const float4*)&Bs[kk][tx * 8 + 4];
#pragma unroll
            for (int i = 0; i < 8; ++i)
#pragma unroll
                for (int j = 0; j < 8; ++j)
                    acc[i][j] = fmaf(a[i], bb[j], acc[i][j]);
        }
        __syncthreads();
    }
#pragma unroll
    for (int i = 0; i < 8; ++i) {
        int m = m_base + ty * 8 + i;
        int bglob = m >> tlog, tl = m & tmask;
#pragma unroll
        for (int j = 0; j < 8; j += 4) {
            int n = n_base + tx * 8 + j;
            int gate = n >> 9, c = n & 511;
            float4 v;
            v.x = acc[i][j + 0] + bias[n + 0];
            v.y = acc[i][j + 1] + bias[n + 1];
            v.z = acc[i][j + 2] + bias[n + 2];
            v.w = acc[i][j + 3] + bias[n + 3];
            size_t addr = (((size_t)tl * 4 + gate) * 32 + bglob) * 512 + c;
            *(float4*)(C + addr) = v;
        }
    }
}

// ---------------------------------------------------------------------------
// Phase 2: FUSED persistent kernel. 256 blocks x 768 threads (1 block/CU).
//  waves 0-7  : R6 LSTM scan (proven 818us structure) with SOFT LDS barriers
//               (s_barrier's compiler-inserted vmcnt(0) drain removed from
//               the step loop -> xp prefetch / out-store acks stay in flight).
//  waves 8-11 : xp GEMM for the NEXT chunk (64x64x16 tiles, own soft-barrier
//               counter). GEMM VALU duty ~13% of chunk -> fits scan's idle.
// Roles share no LDS and no barriers after the single initial __syncthreads.
//
// Scan (verbatim R6 data plan): Wh slice in LDS; h staged once per CU into
// double-buffered LDS; data-poll sync with 3 rotating poisoned h buffers
// (0xFFFFFFFF NaN, unreachable by h=o*tanh(c)); vmcnt(0) drain orders poison
// before the h-store (drain-then-signal). Numerics bit-identical to R6.
// ---------------------------------------------------------------------------
#define NGRP 8
#define BPG  32
#define HSZ  (32 * 512)          // one h buffer (floats)
#define POISON 0xFFFFFFFFu
#define WHST 516                 // padded wh row stride (floats)

__device__ __forceinline__ float ldg_agent_f32(const float* p) {
    return __hip_atomic_load(p, __ATOMIC_RELAXED, __HIP_MEMORY_SCOPE_AGENT);
}

// soft barrier: LDS counter, lgkmcnt-only ordering (no VMEM drain)
__device__ __forceinline__ void soft_bar(unsigned* ctr, bool leader, unsigned target) {
    asm volatile("s_waitcnt lgkmcnt(0)" ::: "memory");   // my LDS writes retired
    if (leader)
        __hip_atomic_fetch_add(ctr, 1u, __ATOMIC_RELAXED, __HIP_MEMORY_SCOPE_WORKGROUP);
    while (__hip_atomic_load(ctr, __ATOMIC_RELAXED, __HIP_MEMORY_SCOPE_WORKGROUP) < target) {}
}

// butterfly reduce step
template<int D, int HALF>
__device__ __forceinline__ void rstep(float* p, int lane) {
    const bool hi = (lane & D) != 0;
#pragma unroll
    for (int i = 0; i < HALF; ++i) {
        float send = hi ? p[i] : p[i + HALF];
        float recv = __shfl_xor(send, D, 64);
        p[i] = (hi ? p[i + HALF] : p[i]) + recv;
    }
}

__global__ __launch_bounds__(768) void lstm_fused(
    const float* __restrict__ xp,   // current chunk [tl][gate 4][B 32][col 512]
    const float* __restrict__ A,    // inputs [32*2048, 512]
    const float* __restrict__ Wi,   // [512, 2048]
    const float* __restrict__ bias, // [2048]
    float* __restrict__ xpn,        // next chunk xp (GEMM output)
    const float* __restrict__ Wh,   // [512, 2048]
    const float* __restrict__ c0,
    const float* __restrict__ h0,
    float* __restrict__ out,        // [32, 2048, 512]
    float* hbuf,                    // [3][32][512]
    float* __restrict__ cbuf,       // [32][512]
    int t0, int T_CH, int ngt, int tlog2)
{
    __shared__ float wh[64 * WHST];             // 132,096 B
    __shared__ float hs[2 * 4 * 512];           //  16,384 B
    __shared__ __align__(16) float As2[16][68]; //   4,352 B
    __shared__ __align__(16) float Bs2[16][68]; //   4,352 B
    __shared__ unsigned scnt, gcnt;

    const int tid  = threadIdx.x;
    const int blk  = blockIdx.x;
    const int g    = blk >> 5;      // group 0..7 (4 batches each)
    const int p    = blk & 31;      // block-in-group (16 cols each)
    const int j0   = p * 16;
    const int lane = tid & 63;
    const int w    = tid >> 6;      // wave 0..11

    if (tid == 0) { scnt = 0u; gcnt = 0u; }

    // ===================== scan-side init (tid < 512) =====================
    int gate = 0, cc = 0, B = 0, col = 0;
    bool low = false, act = false;
    float creg = 0.f, xr = 0.f, xn = 0.f;
    if (tid < 512) {
        const int idx = ((lane & 1) << 4) | ((lane & 2) << 2) | (lane & 4)
                      | ((lane >> 2) & 2) | ((lane >> 4) & 1);
        gate = idx >> 3;
        cc   = (idx >> 2) & 1;
        const int bq = idx & 3;
        B    = 4 * g + bq;
        col  = j0 + 2 * w + cc;
        low  = lane < 32;
        act  = low && ((lane & 3) == 0);

        if (act) {
            size_t o = (size_t)B * 512 + col;
            if (t0 == 0) {
                creg = c0[o];
                float hv = h0[o];
                if (__float_as_uint(hv) == POISON) hv = __uint_as_float(0xFFFFFFFEu);
                __hip_atomic_store(hbuf + o, hv, __ATOMIC_RELAXED, __HIP_MEMORY_SCOPE_AGENT);
            } else {
                creg = cbuf[o];
            }
        }

        // stage Wh slice into LDS (512 threads x 16 iters)
#pragma unroll
        for (int i = 0; i < 16; ++i) {
            int id = tid + i * 512;
            int q4 = id & 3, gt = (id >> 2) & 3, k = id >> 4;
            float4 v = *(const float4*)(Wh + (size_t)k * 2048 + gt * 512 + j0 + q4 * 4);
            int r0 = gt * 16 + q4 * 4;
            wh[(r0 + 0) * WHST + k] = v.x;
            wh[(r0 + 1) * WHST + k] = v.y;
            wh[(r0 + 2) * WHST + k] = v.z;
            wh[(r0 + 3) * WHST + k] = v.w;
        }
        if (low) xr = xp[((size_t)gate * 32 + B) * 512 + col];
    }

    __syncthreads();   // the ONLY workgroup-wide barrier

    if (tid < 512) {
        // ========================== scan role ==========================
        const int sb = w >> 1;          // staging batch
        const int sh = (w & 1) * 256;   // staging half
        unsigned starget = 0;

        for (int tl = 0; tl < T_CH; ++tl) {
            const int t = t0 + tl;
            const int cur = t % 3;
            const int nxt = (t + 1) % 3;
            const int rcy = (t + 2) % 3;

            if (low && (tl + 1 < T_CH))
                xn = xp[((size_t)((tl + 1) * 4 + gate) * 32 + B) * 512 + col];

            // poll own 4 slots of h_t (data IS the signal)
            const float* hsrc = hbuf + (size_t)cur * HSZ
                              + (size_t)(4 * g + sb) * 512 + sh + lane;
            float hvv[4];
            for (;;) {
                bool ok = true;
#pragma unroll
                for (int q = 0; q < 4; ++q) {
                    hvv[q] = ldg_agent_f32(hsrc + q * 64);
                    ok = ok & (__float_as_uint(hvv[q]) != POISON);
                }
                if (ok) break;
                __builtin_amdgcn_s_sleep(1);
            }
            float* hdst = hs + (tl & 1) * 2048 + sb * 512 + sh + lane;
#pragma unroll
            for (int q = 0; q < 4; ++q) hdst[q * 64] = hvv[q];

            // soft barrier: h_t staged (lgkmcnt-only; VMEM stays in flight)
            starget += 8;
            soft_bar(&scnt, lane == 0, starget);

            // poison recycle slot (safe: complete h_t => all group blocks
            // finished step t-1, i.e. consumed h_{t-1})
            if (act)
                __hip_atomic_store(hbuf + (size_t)rcy * HSZ + (size_t)B * 512 + col,
                                   __uint_as_float(POISON),
                                   __ATOMIC_RELAXED, __HIP_MEMORY_SCOPE_AGENT);

            __builtin_amdgcn_s_setprio(1);
            // dot: pp[gate*8 + cc*4 + b] over this lane's 8 k (order = R6)
            const float* hb = hs + (tl & 1) * 2048;
            float4 ha[4], h2[4];
#pragma unroll
            for (int b = 0; b < 4; ++b) {
                ha[b] = *(const float4*)(hb + b * 512 + 4 * lane);
                h2[b] = *(const float4*)(hb + b * 512 + 256 + 4 * lane);
            }
            float pp[32];
#pragma unroll
            for (int i = 0; i < 32; ++i) pp[i] = 0.f;
#pragma unroll
            for (int gt = 0; gt < 4; ++gt)
#pragma unroll
                for (int c2 = 0; c2 < 2; ++c2) {
                    const float* wr = wh + (size_t)(gt * 16 + 2 * w + c2) * WHST + 4 * lane;
                    float4 w0 = *(const float4*)wr;
                    float4 w1 = *(const float4*)(wr + 256);
#pragma unroll
                    for (int b = 0; b < 4; ++b) {
                        float a = pp[gt * 8 + c2 * 4 + b];
                        a = fmaf(ha[b].x, w0.x, a);
                        a = fmaf(ha[b].y, w0.y, a);
                        a = fmaf(ha[b].z, w0.z, a);
                        a = fmaf(ha[b].w, w0.w, a);
                        a = fmaf(h2[b].x, w1.x, a);
                        a = fmaf(h2[b].y, w1.y, a);
                        a = fmaf(h2[b].z, w1.z, a);
                        a = fmaf(h2[b].w, w1.w, a);
                        pp[gt * 8 + c2 * 4 + b] = a;
                    }
                }

            rstep<1, 16>(pp, lane);
            rstep<2, 8>(pp, lane);
            rstep<4, 4>(pp, lane);
            rstep<8, 2>(pp, lane);
            rstep<16, 1>(pp, lane);
            float v0 = pp[0] + __shfl_xor(pp[0], 32, 64);

            // distributed activation + gathers (R6-verified mapping)
            float av = 0.f;
            if (low) {
                float zz = v0 + xr;
                av = (gate == 2) ? tanhf(zz) : 1.f / (1.f + expf(-zz));
            }
            float ag = __shfl_xor(av, 1, 64);
            float af = __shfl_xor(av, 2, 64);
            float ao = __shfl_xor(av, 3, 64);
            __builtin_amdgcn_s_setprio(0);

            float hn = 0.f;
            if (act) {
                float cn = af * creg + av * ag;
                hn = ao * tanhf(cn);
                creg = cn;
            }
            // drain: poison at coherence point BEFORE h_{t+1} visible
            asm volatile("s_waitcnt vmcnt(0)" ::: "memory");
            if (act) {
                __hip_atomic_store(hbuf + (size_t)nxt * HSZ + (size_t)B * 512 + col,
                                   hn, __ATOMIC_RELAXED, __HIP_MEMORY_SCOPE_AGENT);
                out[((size_t)B * TT + t) * 512 + col] = hn;
            }
            if (low) xr = xn;
        }

        if (act) cbuf[(size_t)B * 512 + col] = creg;

    } else if (ngt > 0) {
        // ========================== GEMM role ==========================
        // next chunk xp: rows 32*T_CH, cols 2048; 64x64x16 tiles, 4 waves.
        const int id  = tid - 512;          // 0..255
        const int ty2 = id >> 4, tx2 = id & 15;
        const int tmask2 = T_CH - 1;
        const int t0n = t0 + T_CH;
        unsigned gtarget = 0;

        for (int tile = 0; tile < ngt; ++tile) {
            int tt  = blk * ngt + tile;
            int mt2 = tt >> 5, nt2 = tt & 31;

            // staging roles
            int am = id >> 2, akq = id & 3;
            int arc = mt2 * 64 + am;
            int abg = arc >> tlog2, atl = arc & tmask2;
            const float* arow = A + (size_t)(abg * 2048 + t0n + atl) * DD;
            int bkr = id >> 4, bnq = id & 15;

            float acc2[4][4];
#pragma unroll
            for (int i = 0; i < 4; ++i)
#pragma unroll
                for (int j = 0; j < 4; ++j) acc2[i][j] = 0.f;

            for (int k0 = 0; k0 < DD; k0 += 16) {
                float4 av = *(const float4*)(arow + k0 + 4 * akq);
                float4 bv = *(const float4*)(Wi + (size_t)(k0 + bkr) * 2048
                                             + nt2 * 64 + 4 * bnq);
                As2[akq * 4 + 0][am] = av.x;
                As2[akq * 4 + 1][am] = av.y;
                As2[akq * 4 + 2][am] = av.z;
                As2[akq * 4 + 3][am] = av.w;
                *(float4*)&Bs2[bkr][bnq * 4] = bv;

                gtarget += 4;
                soft_bar(&gcnt, lane == 0, gtarget);   // all 4 waves staged
#pragma unroll
                for (int kk = 0; kk < 16; ++kk) {
                    float4 a4 = *(const float4*)&As2[kk][ty2 * 4];
                    float4 b4 = *(const float4*)&Bs2[kk][tx2 * 4];
                    acc2[0][0] = fmaf(a4.x, b4.x, acc2[0][0]);
                    acc2[0][1] = fmaf(a4.x, b4.y, acc2[0][1]);
                    acc2[0][2] = fmaf(a4.x, b4.z, acc2[0][2]);
                    acc2[0][3] = fmaf(a4.x, b4.w, acc2[0][3]);
                    acc2[1][0] = fmaf(a4.y, b4.x, acc2[1][0]);
                    acc2[1][1] = fmaf(a4.y, b4.y, acc2[1][1]);
                    acc2[1][2] = fmaf(a4.y, b4.z, acc2[1][2]);
                    acc2[1][3] = fmaf(a4.y, b4.w, acc2[1][3]);
                    acc2[2][0] = fmaf(a4.z, b4.x, acc2[2][0]);
                    acc2[2][1] = fmaf(a4.z, b4.y, acc2[2][1]);
                    acc2[2][2] = fmaf(a4.z, b4.z, acc2[2][2]);
                    acc2[2][3] = fmaf(a4.z, b4.w, acc2[2][3]);
                    acc2[3][0] = fmaf(a4.w, b4.x, acc2[3][0]);
                    acc2[3][1] = fmaf(a4.w, b4.y, acc2[3][1]);
                    acc2[3][2] = fmaf(a4.w, b4.z, acc2[3][2]);
                    acc2[3][3] = fmaf(a4.w, b4.w, acc2[3][3]);
                }
                gtarget += 4;
                soft_bar(&gcnt, lane == 0, gtarget);   // all 4 waves done reading
            }

            // epilogue: + bias, store to xpn in scan layout
            int nb = nt2 * 64 + tx2 * 4;
            int gt2 = nb >> 9, c512 = nb & 511;
            float4 bsv = *(const float4*)(bias + nb);
#pragma unroll
            for (int i = 0; i < 4; ++i) {
                int rc = mt2 * 64 + ty2 * 4 + i;
                int bg = rc >> tlog2, tl2 = rc & tmask2;
                float4 v;
                v.x = acc2[i][0] + bsv.x;
                v.y = acc2[i][1] + bsv.y;
                v.z = acc2[i][2] + bsv.z;
                v.w = acc2[i][3] + bsv.w;
                size_t addr = (((size_t)tl2 * 4 + gt2) * 32 + bg) * 512 + c512;
                *(float4*)(xpn + addr) = v;
            }
        }
    }
}

// ---------------------------------------------------------------------------
extern "C" void kernel_launch(void* const* d_in, const int* in_sizes, int n_in,
                              void* d_out, int out_size, void* d_ws, size_t ws_size,
                              hipStream_t stream) {
    const float* inputs = (const float*)d_in[0];
    // d_in[1] = input_paddings: unused (reference discards it)
    const float* c0   = (const float*)d_in[2];
    const float* h0   = (const float*)d_in[3];
    const float* Wi   = (const float*)d_in[4];
    const float* Wh   = (const float*)d_in[5];
    const float* bias = (const float*)d_in[6];
    float* out = (float*)d_out;

    // ws layout (floats): [hbuf 3*HSZ][cbuf HSZ][xpA slab][xpB slab (dbuf)]
    float* ws_f = (float*)d_ws;
    float* hbuf = ws_f;
    float* cbuf = ws_f + 3 * HSZ;
    float* xpA  = ws_f + 4 * HSZ;

    // pick largest T_CH with DOUBLE xp slab (fused-GEMM mode); else serial.
    int T_CH = 0;
    int dbuf = 1;
    for (int tc = 256; tc >= 32; tc >>= 1) {
        if ((size_t)(4 * HSZ + 2 * (size_t)tc * 65536) * sizeof(float) <= ws_size) {
            T_CH = tc; break;
        }
    }
    if (T_CH == 0) {
        dbuf = 0;
        T_CH = 256;
        while (T_CH > 32 &&
               (size_t)(4 * HSZ + (size_t)T_CH * 65536) * sizeof(float) > ws_size)
            T_CH >>= 1;
    }
    const int tlog = 31 - __builtin_clz((unsigned)T_CH);
    float* xpB = dbuf ? (xpA + (size_t)T_CH * 65536) : xpA;
    const int nch = TT / T_CH;

    // poison all 3 h buffers before t0=0 (scan fills buf[0] in-kernel)
    hipMemsetAsync(hbuf, 0xFF, (size_t)(3 * HSZ) * sizeof(float), stream);

    // prologue: chunk 0 xp -> slab A
    dim3 g1(2048 / BN, (32 * T_CH) / BM);
    xproj_gemm<<<g1, 256, 0, stream>>>(inputs, Wi, bias, xpA, 0, T_CH - 1, tlog);

    for (int n = 0; n < nch; ++n) {
        float* cur = (n & 1) ? xpB : xpA;          // == xpA when !dbuf
        float* nxt = ((n + 1) & 1) ? xpB : xpA;
        int ngt = (dbuf && (n + 1 < nch)) ? (T_CH / 16) : 0;

        if (!dbuf && n > 0)
            xproj_gemm<<<g1, 256, 0, stream>>>(inputs, Wi, bias, xpA,
                                               n * T_CH, T_CH - 1, tlog);

        const float* cur_c = cur;
        float* nxt_m = nxt;
        int t0_arg = n * T_CH, tch_arg = T_CH, ngt_arg = ngt, tlog_arg = tlog;
        void* args[] = { (void*)&cur_c, (void*)&inputs, (void*)&Wi, (void*)&bias,
                         (void*)&nxt_m, (void*)&Wh, (void*)&c0, (void*)&h0,
                         (void*)&out, (void*)&hbuf, (void*)&cbuf,
                         (void*)&t0_arg, (void*)&tch_arg, (void*)&ngt_arg,
                         (void*)&tlog_arg };
        hipLaunchCooperativeKernel((const void*)lstm_fused, dim3(NGRP * BPG),
                                   dim3(768), args, 0, stream);
    }
}

// Round 9
// 7720.658 us; speedup vs baseline: 3.8741x; 1.0761x over previous
//
#include <hip/hip_runtime.h>
#include <cstdint>
#include <cstddef>

// Problem dims: B=32, T=2048, D=512, H=512, 4H=2048
#define TT 2048
#define DD 512

// ---------------------------------------------------------------------------
// Phase 1 (chunked): xp = inputs @ Wi + b, layout: xp[tl][gate 4][B 32][col 512]
// fp32 vector GEMM, 128x128x16 tiles, 8x8 per thread.  (R6's proven version)
// ---------------------------------------------------------------------------
#define BM 128
#define BN 128
#define BK 16

__global__ __launch_bounds__(256) void xproj_gemm(
    const float* __restrict__ A,    // [32*2048, 512]
    const float* __restrict__ W,    // [512, 2048]
    const float* __restrict__ bias, // [2048]
    float* __restrict__ C,          // xp chunk
    int t0, int tmask, int tlog)    // T_CH = tmask+1 = 1<<tlog
{
    __shared__ __align__(16) float As[BK][BM + 4];   // [k][m], transposed on load
    __shared__ __align__(16) float Bs[BK][BN + 4];   // [k][n]
    const int tid = threadIdx.x;
    const int nt = blockIdx.x;
    const int mt = blockIdx.y;
    const int m_base = mt * BM;
    const int n_base = nt * BN;
    const int ty = tid >> 4;
    const int tx = tid & 15;

    float acc[8][8];
#pragma unroll
    for (int i = 0; i < 8; ++i)
#pragma unroll
        for (int j = 0; j < 8; ++j) acc[i][j] = 0.f;

    for (int k0 = 0; k0 < DD; k0 += BK) {
#pragma unroll
        for (int j = 0; j < 2; ++j) {
            int idx = tid * 2 + j;             // 0..511
            int rowl = idx >> 2, q = idx & 3;  // A: 128 rows x 4 float4
            int rc = m_base + rowl;            // chunk-local row
            int rg = ((rc >> tlog) << 11) + t0 + (rc & tmask);
            float4 av = *(const float4*)(A + (size_t)rg * DD + k0 + q * 4);
            As[q * 4 + 0][rowl] = av.x;
            As[q * 4 + 1][rowl] = av.y;
            As[q * 4 + 2][rowl] = av.z;
            As[q * 4 + 3][rowl] = av.w;
            int kr = idx >> 5, nq = idx & 31;  // B: 16 rows x 32 float4
            *(float4*)&Bs[kr][nq * 4] =
                *(const float4*)(W + (size_t)(k0 + kr) * 2048 + n_base + nq * 4);
        }
        __syncthreads();
#pragma unroll
        for (int kk = 0; kk < BK; ++kk) {
            float a[8], bb[8];
            *(float4*)&a[0]  = *(const float4*)&As[kk][ty * 8];
            *(float4*)&a[4]  = *(const float4*)&As[kk][ty * 8 + 4];
            *(float4*)&bb[0] = *(const float4*)&Bs[kk][tx * 8];
            *(float4*)&bb[4] = *(const float4*)&Bs[kk][tx * 8 + 4];
#pragma unroll
            for (int i = 0; i < 8; ++i)
#pragma unroll
                for (int j = 0; j < 8; ++j)
                    acc[i][j] = fmaf(a[i], bb[j], acc[i][j]);
        }
        __syncthreads();
    }
#pragma unroll
    for (int i = 0; i < 8; ++i) {
        int m = m_base + ty * 8 + i;
        int bglob = m >> tlog, tl = m & tmask;
#pragma unroll
        for (int j = 0; j < 8; j += 4) {
            int n = n_base + tx * 8 + j;
            int gate = n >> 9, c = n & 511;
            float4 v;
            v.x = acc[i][j + 0] + bias[n + 0];
            v.y = acc[i][j + 1] + bias[n + 1];
            v.z = acc[i][j + 2] + bias[n + 2];
            v.w = acc[i][j + 3] + bias[n + 3];
            size_t addr = (((size_t)tl * 4 + gate) * 32 + bglob) * 512 + c;
            *(float4*)(C + addr) = v;
        }
    }
}

// ---------------------------------------------------------------------------
// Phase 2: persistent LSTM scan = R6 (818us proven) + sync-path surgery:
//  (a) in-loop __syncthreads -> soft LDS-counter barrier (lgkmcnt-only).
//      The hard barrier's implicit vmcnt(0) forced every wave to wait for
//      the xp HBM prefetch issued moments earlier, every step.
//  (b) end-of-step vmcnt(0) drain REMOVED. Ordering is structural: vmcnt
//      retires in issue order, and consuming the next poll's load values
//      forces retirement of all older VMEM -- including the poison issued a
//      full step before the h-store to the same slot. The drain only delayed
//      our h publication (the group critical path).
//  (c) butterfly xor1/xor2/xor3 via DPP quad_perm (VALU) instead of
//      __shfl_xor (LDS pipe) -- relieves the contended LDS pipe.
//      Bit-identical arithmetic (same pairs, same order).
//
// Geometry (R6): 8 groups x 32 blocks x 512 threads (1 block/CU). Group g
// owns batches [4g,4g+4). Block p owns cols [16p,16p+16). Wave w owns cols
// {16p+2w,16p+2w+1}, all 4 gates, all 4 batches. Lane l owns k in
// {4l..4l+3} U {256+4l..256+4l+3}.
//
// Poison protocol (R4/R6-proven): h rotates through 3 buffers; slot owner
// poisons its recycle slot after the poll (complete h_t proves all group
// blocks consumed h_{t-1}); poison lands before the h-store to that slot via
// in-order vmcnt retirement through the next poll. 0xFFFFFFFF is NaN,
// unreachable by h = o*tanh(c) in (-1,1).
// ---------------------------------------------------------------------------
#define NGRP 8
#define BPG  32
#define HSZ  (32 * 512)          // one h buffer (floats)
#define POISON 0xFFFFFFFFu
#define WHST 516                 // padded wh row stride (floats)

__device__ __forceinline__ float ldg_agent_f32(const float* p) {
    return __hip_atomic_load(p, __ATOMIC_RELAXED, __HIP_MEMORY_SCOPE_AGENT);
}

// DPP quad_perm lane exchange (VALU pipe; exact xor within quads)
template<int CTRL>
__device__ __forceinline__ float dppf(float x) {
    return __int_as_float(
        __builtin_amdgcn_update_dpp(0, __float_as_int(x), CTRL, 0xf, 0xf, true));
}
// quad_perm ctrl: xor1 = [1,0,3,2] = 0xB1; xor2 = [2,3,0,1] = 0x4E;
//                 xor3 = [3,2,1,0] = 0x1B

// soft barrier: LDS counter; orders LDS (staging) only -- VMEM stays in flight
__device__ __forceinline__ void soft_bar(unsigned* ctr, bool leader, unsigned target) {
    asm volatile("s_waitcnt lgkmcnt(0)" ::: "memory");   // my ds_writes retired
    if (leader)
        __hip_atomic_fetch_add(ctr, 1u, __ATOMIC_RELAXED, __HIP_MEMORY_SCOPE_WORKGROUP);
    while (__hip_atomic_load(ctr, __ATOMIC_RELAXED, __HIP_MEMORY_SCOPE_WORKGROUP) < target)
        __builtin_amdgcn_s_sleep(1);
    __builtin_amdgcn_sched_barrier(0);   // no hoisting of hs reads above the spin
}

// butterfly reduce step: halve the live value count across lanes differing in bit D
template<int D, int HALF>
__device__ __forceinline__ void rstep(float* p, int lane) {
    const bool hi = (lane & D) != 0;
#pragma unroll
    for (int i = 0; i < HALF; ++i) {
        float send = hi ? p[i] : p[i + HALF];
        float recv;
        if constexpr (D == 1)      recv = dppf<0xB1>(send);
        else if constexpr (D == 2) recv = dppf<0x4E>(send);
        else                       recv = __shfl_xor(send, D, 64);
        p[i] = (hi ? p[i + HALF] : p[i]) + recv;
    }
}

__global__ __launch_bounds__(512) void lstm_scan(
    const float* __restrict__ xp,   // [tl][gate 4][B 32][col 512]
    const float* __restrict__ Wh,   // [512, 2048]
    const float* __restrict__ c0,   // [32, 512]
    const float* __restrict__ h0,   // [32, 512]
    float* __restrict__ out,        // [32, 2048, 512]
    float* hbuf,                    // [3][32][512] rotating (persists)
    float* __restrict__ cbuf,       // [32][512] c-state (persists)
    int t0, int T_CH)
{
    __shared__ float wh[64 * WHST];   // [gate*16 + local_col][k]  132,096 B
    __shared__ float hs[2 * 4 * 512]; // double-buffered [buf][b][k] 16,384 B
    __shared__ unsigned scnt;

    const int tid  = threadIdx.x;
    const int blk  = blockIdx.x;
    const int g    = blk >> 5;      // group 0..7 (4 batches each)
    const int p    = blk & 31;      // block-in-group (16 cols each)
    const int j0   = p * 16;
    const int lane = tid & 63;
    const int w    = tid >> 6;      // wave 0..7

    // lane<32 role decode: idx = bitrev5(lane) = gate*8 + cc*4 + b
    const int idx = ((lane & 1) << 4) | ((lane & 2) << 2) | (lane & 4)
                  | ((lane >> 2) & 2) | ((lane >> 4) & 1);
    const int gate = idx >> 3;
    const int cc   = (idx >> 2) & 1;
    const int bq   = idx & 3;
    const int B    = 4 * g + bq;
    const int col  = j0 + 2 * w + cc;
    const bool low = lane < 32;
    const bool act = low && ((lane & 3) == 0);   // gate==0 owner lanes

    if (tid == 0) scnt = 0u;

    // ---- h0 / creg init (issue h0 stores FIRST so peers' polls clear) ----
    float creg = 0.f;
    if (act) {
        size_t o = (size_t)B * 512 + col;
        if (t0 == 0) {
            creg = c0[o];
            float hv = h0[o];
            if (__float_as_uint(hv) == POISON) hv = __uint_as_float(0xFFFFFFFEu);
            __hip_atomic_store(hbuf + o, hv, __ATOMIC_RELAXED, __HIP_MEMORY_SCOPE_AGENT);
        } else {
            creg = cbuf[o];   // h_{t0} already in hbuf[t0%3] from prev chunk
        }
    }

    // ---- stage Wh slice into LDS (once per launch) ----
#pragma unroll
    for (int i = 0; i < 16; ++i) {
        int id = tid + i * 512;
        int q4 = id & 3, gt = (id >> 2) & 3, k = id >> 4;
        float4 v = *(const float4*)(Wh + (size_t)k * 2048 + gt * 512 + j0 + q4 * 4);
        int r0 = gt * 16 + q4 * 4;
        wh[(r0 + 0) * WHST + k] = v.x;
        wh[(r0 + 1) * WHST + k] = v.y;
        wh[(r0 + 2) * WHST + k] = v.z;
        wh[(r0 + 3) * WHST + k] = v.w;
    }

    // staging role: batch sb = w>>1, half sh = (w&1)*256, 4 slots (q*64+lane)
    const int sb = w >> 1;
    const int sh = (w & 1) * 256;

    // xp prefetch for tl=0
    float xr = 0.f, xn = 0.f;
    if (low) xr = xp[((size_t)gate * 32 + B) * 512 + col];

    __syncthreads();   // one-time: wh ready + scnt published

    unsigned starget = 0;

    for (int tl = 0; tl < T_CH; ++tl) {
        const int t = t0 + tl;
        const int cur = t % 3;             // read h_t
        const int nxt = (t + 1) % 3;       // write h_{t+1}
        const int rcy = (t + 2) % 3;       // poison own slot (holds dead h_{t-1})

        // issue next-step xp prefetch (stays in flight across the whole step:
        // nothing waits on it until the NEXT step's poll)
        if (low && (tl + 1 < T_CH))
            xn = xp[((size_t)((tl + 1) * 4 + gate) * 32 + B) * 512 + col];

        // ---- poll own 4 slots of h_t (data IS the signal). Consuming these
        // values forces in-order vmcnt retirement of ALL older VMEM: the
        // previous step's poison, h-store, out-store, xp load. ----
        const float* hsrc = hbuf + (size_t)cur * HSZ
                          + (size_t)(4 * g + sb) * 512 + sh + lane;
        float hvv[4];
        for (;;) {
            bool ok = true;
#pragma unroll
            for (int q = 0; q < 4; ++q) {
                hvv[q] = ldg_agent_f32(hsrc + q * 64);
                ok = ok & (__float_as_uint(hvv[q]) != POISON);
            }
            if (ok) break;
            __builtin_amdgcn_s_sleep(1);
        }
        float* hdst = hs + (tl & 1) * 2048 + sb * 512 + sh + lane;
#pragma unroll
        for (int q = 0; q < 4; ++q) hdst[q * 64] = hvv[q];

        // soft barrier: h_t staged block-wide (lgkmcnt-only; VMEM in flight)
        starget += 8;
        soft_bar(&scnt, lane == 0, starget);

        // ---- poison recycle slot (safe: complete h_t => every group block
        // finished step t-1, i.e. its poll of buffer rcy is done). The store
        // must land before OUR h_{t+2} store to the same slot -- guaranteed
        // by in-order retirement through step t+1's poll. ----
        if (act)
            __hip_atomic_store(hbuf + (size_t)rcy * HSZ + (size_t)B * 512 + col,
                               __uint_as_float(POISON),
                               __ATOMIC_RELAXED, __HIP_MEMORY_SCOPE_AGENT);
        asm volatile("" ::: "memory");   // pin issue order (poison precedes dot+store)

        // ---- dot: pp[gate*8 + cc*4 + b] over this lane's 8 k (order = R6) ----
        const float* hb = hs + (tl & 1) * 2048;
        float4 ha[4], h2[4];
#pragma unroll
        for (int b = 0; b < 4; ++b) {
            ha[b] = *(const float4*)(hb + b * 512 + 4 * lane);
            h2[b] = *(const float4*)(hb + b * 512 + 256 + 4 * lane);
        }
        float pp[32];
#pragma unroll
        for (int i = 0; i < 32; ++i) pp[i] = 0.f;
#pragma unroll
        for (int gt = 0; gt < 4; ++gt)
#pragma unroll
            for (int c2 = 0; c2 < 2; ++c2) {
                const float* wr = wh + (size_t)(gt * 16 + 2 * w + c2) * WHST + 4 * lane;
                float4 w0 = *(const float4*)wr;
                float4 w1 = *(const float4*)(wr + 256);
#pragma unroll
                for (int b = 0; b < 4; ++b) {
                    float a = pp[gt * 8 + c2 * 4 + b];
                    a = fmaf(ha[b].x, w0.x, a);
                    a = fmaf(ha[b].y, w0.y, a);
                    a = fmaf(ha[b].z, w0.z, a);
                    a = fmaf(ha[b].w, w0.w, a);
                    a = fmaf(h2[b].x, w1.x, a);
                    a = fmaf(h2[b].y, w1.y, a);
                    a = fmaf(h2[b].z, w1.z, a);
                    a = fmaf(h2[b].w, w1.w, a);
                    pp[gt * 8 + c2 * 4 + b] = a;
                }
            }

        // ---- butterfly: lane ends with total for idx = bitrev5(lane&31) ----
        rstep<1, 16>(pp, lane);     // DPP
        rstep<2, 8>(pp, lane);      // DPP
        rstep<4, 4>(pp, lane);
        rstep<8, 2>(pp, lane);
        rstep<16, 1>(pp, lane);
        float v0 = pp[0] + __shfl_xor(pp[0], 32, 64);

        // ---- distributed activation: each low lane applies its gate's fn ----
        float av = 0.f;
        if (low) {
            float zz = v0 + xr;
            av = (gate == 2) ? tanhf(zz) : 1.f / (1.f + expf(-zz));
        }
        // gathers (R6-verified mapping), DPP quad_perm: xor1->g, xor2->f, xor3->o
        float ag = dppf<0xB1>(av);
        float af = dppf<0x4E>(av);
        float ao = dppf<0x1B>(av);

        float hn = 0.f;
        if (act) {
            float cn = af * creg + av * ag;   // sf*c + si*tg
            hn = ao * tanhf(cn);
            creg = cn;
            // h-store issues IMMEDIATELY (no drain -- see header (b))
            __hip_atomic_store(hbuf + (size_t)nxt * HSZ + (size_t)B * 512 + col,
                               hn, __ATOMIC_RELAXED, __HIP_MEMORY_SCOPE_AGENT);
            out[((size_t)B * TT + t) * 512 + col] = hn;   // post-critical-path
        }
        if (low) xr = xn;
    }

    // persist c for next chunk launch (plain; kernel-boundary coherence)
    if (act) cbuf[(size_t)B * 512 + col] = creg;
}

// ---------------------------------------------------------------------------
extern "C" void kernel_launch(void* const* d_in, const int* in_sizes, int n_in,
                              void* d_out, int out_size, void* d_ws, size_t ws_size,
                              hipStream_t stream) {
    const float* inputs = (const float*)d_in[0];
    // d_in[1] = input_paddings: unused (reference discards it)
    const float* c0   = (const float*)d_in[2];
    const float* h0   = (const float*)d_in[3];
    const float* Wi   = (const float*)d_in[4];
    const float* Wh   = (const float*)d_in[5];
    const float* bias = (const float*)d_in[6];
    float* out = (float*)d_out;

    // ws layout (floats): [hbuf 3*HSZ][cbuf HSZ][xp]
    float* ws_f = (float*)d_ws;
    float* hbuf = ws_f;                              // 49152 floats
    float* cbuf = ws_f + 3 * HSZ;                    // 16384 floats
    float* xp   = ws_f + 4 * HSZ;                    // offset 65536 (16B aligned)
    const size_t extras_bytes = (size_t)(4 * HSZ) * sizeof(float);

    // pick largest T-chunk (pow2, <=256) whose xp slab fits in ws
    int T_CH = 256;
    while (T_CH > 32 &&
           extras_bytes + (size_t)T_CH * 65536 * sizeof(float) > ws_size)
        T_CH >>= 1;
    int tlog = 31 - __builtin_clz((unsigned)T_CH);

    // poison all 3 h buffers (0xFF bytes -> 0xFFFFFFFF words) before t0=0;
    // the scan kernel fills buf[0] with h0 in-kernel (polling is the sync).
    hipMemsetAsync(hbuf, 0xFF, (size_t)(3 * HSZ) * sizeof(float), stream);

    for (int t0 = 0; t0 < TT; t0 += T_CH) {
        dim3 g1(2048 / BN, (32 * T_CH) / BM);
        xproj_gemm<<<g1, 256, 0, stream>>>(inputs, Wi, bias, xp, t0, T_CH - 1, tlog);

        const float* xp_c = xp;
        int t0_arg = t0, tch_arg = T_CH;
        void* args[] = { (void*)&xp_c, (void*)&Wh, (void*)&c0, (void*)&h0,
                         (void*)&out, (void*)&hbuf, (void*)&cbuf,
                         (void*)&t0_arg, (void*)&tch_arg };
        hipLaunchCooperativeKernel((const void*)lstm_scan, dim3(NGRP * BPG), dim3(512),
                                   args, 0, stream);
    }
}